// Round 1
// baseline (6657.750 us; speedup 1.0000x reference)
//
#include <hip/hip_runtime.h>
#include <hip/hip_bf16.h>

#define N_VOX 150000
#define CH 32
#define KVOL 27
#define NCLS 20
#define PPB 128                      // pairs per block in spconv kernel
#define NB ((N_VOX + PPB - 1) / PPB) // 1172 blocks per kernel offset

// ---------------------------------------------------------------------------
// spconv scatter kernel: for 128 (gather,scatter) pairs of one kernel offset k:
//   dst[s[i]] += src[g[i]] @ W[k]      (atomic f32 adds)
// Block = 256 threads. Each thread: 4 pairs x 4 couts outer-product tile.
// ---------------------------------------------------------------------------
__global__ __launch_bounds__(256) void k_spconv(
    const float* __restrict__ src, float* __restrict__ dst,
    const int* __restrict__ gidx, const int* __restrict__ sidx,
    const float* __restrict__ W) {
  __shared__ float sW[CH][CH];        // 4 KB: W[k][cin][cout]
  __shared__ float sXT[CH][PPB + 4];  // 16.5 KB transposed gathered rows (row=cin)
  __shared__ int   sS[PPB];

  const int tid  = threadIdx.x;
  const int k    = blockIdx.x / NB;
  const int base = (blockIdx.x % NB) * PPB;

  // stage W[k] (1024 floats, 256 x float4)
  {
    const float4* wv = (const float4*)(W + k * CH * CH);
    ((float4*)sW)[tid] = wv[tid];
  }

  // gather 128 rows (each 128 B) into LDS, transposed.
  // idx in [0,1024): row = idx>>3 (0..127), q4 = idx&7 (which float4 of the row)
#pragma unroll
  for (int u = 0; u < 4; u++) {
    int idx = tid * 4 + u;
    int row = idx >> 3;
    int q4  = idx & 7;
    int pr  = base + row;
    if (pr < N_VOX) {
      int gi = gidx[k * N_VOX + pr];
      float4 xv = *(const float4*)(src + gi * CH + q4 * 4);
      sXT[q4 * 4 + 0][row] = xv.x;
      sXT[q4 * 4 + 1][row] = xv.y;
      sXT[q4 * 4 + 2][row] = xv.z;
      sXT[q4 * 4 + 3][row] = xv.w;
    }
  }
  if (tid < PPB) {
    int pr = base + tid;
    sS[tid] = (pr < N_VOX) ? sidx[k * N_VOX + pr] : -1;
  }
  __syncthreads();

  const int q  = tid & 7;   // cout group: couts q*4 .. q*4+3
  const int pg = tid >> 3;  // pair group: pairs pg*4 .. pg*4+3

  float acc[4][4] = {{0.f}};
#pragma unroll
  for (int ci = 0; ci < CH; ci++) {
    float4 xv = *(const float4*)&sXT[ci][pg * 4];
    float4 wv = *(const float4*)&sW[ci][q * 4];
    float xr[4] = {xv.x, xv.y, xv.z, xv.w};
    float wr[4] = {wv.x, wv.y, wv.z, wv.w};
#pragma unroll
    for (int r = 0; r < 4; r++)
#pragma unroll
      for (int j = 0; j < 4; j++)
        acc[r][j] = fmaf(xr[r], wr[j], acc[r][j]);
  }

#pragma unroll
  for (int r = 0; r < 4; r++) {
    int so = sS[pg * 4 + r];
    if (so >= 0) {
      float* dp = dst + so * CH + q * 4;
      atomicAdd(dp + 0, acc[r][0]);
      atomicAdd(dp + 1, acc[r][1]);
      atomicAdd(dp + 2, acc[r][2]);
      atomicAdd(dp + 3, acc[r][3]);
    }
  }
}

// ---------------------------------------------------------------------------
// x = relu(x + b[c]) over [N, CH], float4
// ---------------------------------------------------------------------------
__global__ __launch_bounds__(256) void k_bias_relu(float* __restrict__ x,
                                                   const float* __restrict__ b) {
  int i = blockIdx.x * blockDim.x + threadIdx.x;
  const int n4 = N_VOX * CH / 4;
  if (i >= n4) return;
  float4 v = ((float4*)x)[i];
  int c0 = (i & 7) * 4;
  v.x = fmaxf(v.x + b[c0 + 0], 0.f);
  v.y = fmaxf(v.y + b[c0 + 1], 0.f);
  v.z = fmaxf(v.z + b[c0 + 2], 0.f);
  v.w = fmaxf(v.w + b[c0 + 3], 0.f);
  ((float4*)x)[i] = v;
}

// ---------------------------------------------------------------------------
// out[i][j] = sum_c (A[i][c] + B[i][c]) * Wl[c][j] + bl[j]
// one thread per row (computes all 20 logits)
// ---------------------------------------------------------------------------
__global__ __launch_bounds__(256) void k_logits(
    const float* __restrict__ A, const float* __restrict__ B,
    const float* __restrict__ Wl, const float* __restrict__ bl,
    float* __restrict__ out) {
  __shared__ float sWl[CH * NCLS];
  __shared__ float sbl[NCLS];
  int tid = threadIdx.x;
  if (tid < CH * NCLS / 4) ((float4*)sWl)[tid] = ((const float4*)Wl)[tid];
  if (tid < NCLS) sbl[tid] = bl[tid];
  __syncthreads();

  int row = blockIdx.x * blockDim.x + tid;
  if (row >= N_VOX) return;

  float acc[NCLS];
#pragma unroll
  for (int j = 0; j < NCLS; j++) acc[j] = sbl[j];

  const float4* ra = (const float4*)(A + row * CH);
  const float4* rb = (const float4*)(B + row * CH);
#pragma unroll
  for (int c4 = 0; c4 < CH / 4; c4++) {
    float4 va = ra[c4];
    float4 vb = rb[c4];
    float x[4] = {va.x + vb.x, va.y + vb.y, va.z + vb.z, va.w + vb.w};
#pragma unroll
    for (int u = 0; u < 4; u++) {
      int c = c4 * 4 + u;
#pragma unroll
      for (int j = 0; j < NCLS; j++) acc[j] = fmaf(x[u], sWl[c * NCLS + j], acc[j]);
    }
  }
  // 20 floats = 5 float4 (row*20*4 B = 80 B, 16B-aligned)
  float4* op = (float4*)(out + row * NCLS);
#pragma unroll
  for (int j5 = 0; j5 < NCLS / 4; j5++) {
    float4 v;
    v.x = acc[j5 * 4 + 0];
    v.y = acc[j5 * 4 + 1];
    v.z = acc[j5 * 4 + 2];
    v.w = acc[j5 * 4 + 3];
    op[j5] = v;
  }
}

// ---------------------------------------------------------------------------
extern "C" void kernel_launch(void* const* d_in, const int* in_sizes, int n_in,
                              void* d_out, int out_size, void* d_ws, size_t ws_size,
                              hipStream_t stream) {
  const float* in_feats = (const float*)d_in[0];
  const int*   ga       = (const int*)d_in[1];
  const int*   sa       = (const int*)d_in[2];
  const int*   gb       = (const int*)d_in[3];
  const int*   sb       = (const int*)d_in[4];
  const float* w1       = (const float*)d_in[5];
  const float* b1       = (const float*)d_in[6];
  const float* w1_2     = (const float*)d_in[7];
  const float* b1_2     = (const float*)d_in[8];
  const float* w2       = (const float*)d_in[9];
  const float* b2       = (const float*)d_in[10];
  const float* w3       = (const float*)d_in[11];
  const float* b3       = (const float*)d_in[12];
  const float* wl       = (const float*)d_in[13];
  const float* bl       = (const float*)d_in[14];
  float* out = (float*)d_out;

  const size_t nc = (size_t)N_VOX * CH;
  float* bufA = (float*)d_ws;
  float* bufB = bufA + nc;
  float* bufC = bufB + nc;
  const size_t nc_bytes = nc * sizeof(float);

  dim3 blk(256);
  const int grid_sp = KVOL * NB;
  const int grid_ew = (int)((nc / 4 + 255) / 256);
  const int grid_lg = (N_VOX + 255) / 256;

  // L1: shortcut = relu(spconv(in, rb_a, w1, b1)) -> bufA
  hipMemsetAsync(bufA, 0, nc_bytes, stream);
  k_spconv<<<grid_sp, blk, 0, stream>>>(in_feats, bufA, ga, sa, w1);
  k_bias_relu<<<grid_ew, blk, 0, stream>>>(bufA, b1);

  // L2: shortcut = relu(spconv(bufA, rb_b, w1_2, b1_2)) -> bufB
  hipMemsetAsync(bufB, 0, nc_bytes, stream);
  k_spconv<<<grid_sp, blk, 0, stream>>>(bufA, bufB, gb, sb, w1_2);
  k_bias_relu<<<grid_ew, blk, 0, stream>>>(bufB, b1_2);

  // L3: resA = relu(spconv(in, rb_b, w2, b2)) -> bufC
  hipMemsetAsync(bufC, 0, nc_bytes, stream);
  k_spconv<<<grid_sp, blk, 0, stream>>>(in_feats, bufC, gb, sb, w2);
  k_bias_relu<<<grid_ew, blk, 0, stream>>>(bufC, b2);

  // L4: resA = relu(spconv(bufC, rb_a, w3, b3)) -> bufA (free after L2)
  hipMemsetAsync(bufA, 0, nc_bytes, stream);
  k_spconv<<<grid_sp, blk, 0, stream>>>(bufC, bufA, ga, sa, w3);
  k_bias_relu<<<grid_ew, blk, 0, stream>>>(bufA, b3);

  // final: out = (bufB + bufA) @ wl + bl
  k_logits<<<grid_lg, blk, 0, stream>>>(bufB, bufA, wl, bl, out);
}

// Round 2
// 3911.576 us; speedup vs baseline: 1.7021x; 1.7021x over previous
//
#include <hip/hip_runtime.h>
#include <hip/hip_bf16.h>

#define N_VOX 150000
#define CH 32
#define KVOL 27
#define NCLS 20
#define TOT (KVOL * N_VOX)          // 4,050,000 rulebook entries
#define MPAD 150016                 // N_VOX padded to 256
#define NPART 586                   // MPAD / 256
#define WSTRIDE 520                 // u32 stride per k in LDS W (512 + 8 pad: breaks bank alias)

// ============================ rulebook inversion ============================

__global__ __launch_bounds__(256) void k_hist(const int* __restrict__ sidx,
                                              int* __restrict__ cnt) {
  int e = blockIdx.x * 256 + threadIdx.x;
  if (e < TOT) atomicAdd(&cnt[sidx[e]], 1);
}

__global__ __launch_bounds__(256) void k_scan1(const int* __restrict__ cnt,
                                               int* __restrict__ tmp,
                                               int* __restrict__ part) {
  __shared__ int sb[256];
  int t = threadIdx.x;
  int gt = blockIdx.x * 256 + t;
  int v = cnt[gt];                       // cnt sized MPAD, padding zeroed
  sb[t] = v;
  __syncthreads();
  for (int s = 1; s < 256; s <<= 1) {
    int a = (t >= s) ? sb[t - s] : 0;
    __syncthreads();
    sb[t] += a;
    __syncthreads();
  }
  tmp[gt] = sb[t] - v;                   // exclusive within block
  if (t == 255) part[blockIdx.x] = sb[t];
}

__global__ __launch_bounds__(1024) void k_scan2(int* __restrict__ part) {
  __shared__ int sb[1024];
  int t = threadIdx.x;
  int v = (t < NPART) ? part[t] : 0;
  sb[t] = v;
  __syncthreads();
  for (int s = 1; s < 1024; s <<= 1) {
    int a = (t >= s) ? sb[t - s] : 0;
    __syncthreads();
    sb[t] += a;
    __syncthreads();
  }
  if (t < NPART) part[t] = sb[t] - v;    // exclusive block offsets
}

__global__ __launch_bounds__(256) void k_scan3(const int* __restrict__ tmp,
                                               const int* __restrict__ part,
                                               int* __restrict__ off) {
  int gt = blockIdx.x * 256 + threadIdx.x;
  off[gt] = tmp[gt] + part[blockIdx.x];
}

__global__ __launch_bounds__(256) void k_fill(const int* __restrict__ gidx,
                                              const int* __restrict__ sidx,
                                              const int* __restrict__ off,
                                              int* __restrict__ cur,
                                              int* __restrict__ pl) {
  int e = blockIdx.x * 256 + threadIdx.x;
  if (e >= TOT) return;
  int k = e / N_VOX;                     // compiler magic-div
  int s = sidx[e];
  int pos = atomicAdd(&cur[s], 1);
  pl[off[s] + pos] = (gidx[e] << 5) | k;
}

// -------- row leveling: sort rows by entry count (descending) --------
__global__ __launch_bounds__(256) void k_lvlhist(const int* __restrict__ off,
                                                 int* __restrict__ bins) {
  int t = blockIdx.x * 256 + threadIdx.x;
  if (t >= N_VOX) return;
  int c = off[t + 1] - off[t];
  if (c > 255) c = 255;
  atomicAdd(&bins[c], 1);
}

__global__ __launch_bounds__(256) void k_lvlscan(const int* __restrict__ bins,
                                                 int* __restrict__ base) {
  __shared__ int sb[256];
  int t = threadIdx.x;
  int rt = 255 - t;
  int v = bins[rt];
  sb[t] = v;
  __syncthreads();
  for (int s = 1; s < 256; s <<= 1) {
    int a = (t >= s) ? sb[t - s] : 0;
    __syncthreads();
    sb[t] += a;
    __syncthreads();
  }
  base[rt] = sb[t] - v;                  // sum of bins with count > rt
}

__global__ __launch_bounds__(256) void k_lvlplace(const int* __restrict__ off,
                                                  const int* __restrict__ base,
                                                  int* __restrict__ bcur,
                                                  int* __restrict__ perm) {
  int t = blockIdx.x * 256 + threadIdx.x;
  if (t >= N_VOX) return;
  int c = off[t + 1] - off[t];
  if (c > 255) c = 255;
  int pos = atomicAdd(&bcur[c], 1);
  perm[base[c] + pos] = t;
}

// ============================ fused conv kernel =============================
// Block = 256 threads = 32 row-groups of 8 lanes; lane q owns couts 4q..4q+3.
// W (all 27 offsets) staged in LDS as packed bf16 pairs. CSR gather, fp32
// accumulate, fused bias+ReLU, one coalesced row write. No atomics.

__device__ __forceinline__ unsigned int pk_bf16(float a, float b) {
  unsigned int ua = __float_as_uint(a), ub = __float_as_uint(b);
  ua = ua + 0x7FFFu + ((ua >> 16) & 1u);     // RNE
  ub = ub + 0x7FFFu + ((ub >> 16) & 1u);
  return (ub & 0xFFFF0000u) | (ua >> 16);
}

#define STEP1(xs, ci) { \
  uint2 wv_ = *(const uint2*)&sWu[kbase + (ci) * 16 + q2]; \
  acc.x = fmaf((xs), __uint_as_float(wv_.x << 16), acc.x); \
  acc.y = fmaf((xs), __uint_as_float(wv_.x & 0xFFFF0000u), acc.y); \
  acc.z = fmaf((xs), __uint_as_float(wv_.y << 16), acc.z); \
  acc.w = fmaf((xs), __uint_as_float(wv_.y & 0xFFFF0000u), acc.w); }

#define C4(Xv, cb) { STEP1(Xv.x, cb) STEP1(Xv.y, (cb)+1) STEP1(Xv.z, (cb)+2) STEP1(Xv.w, (cb)+3) }

#define CALL32(A) { C4(A##0, 0) C4(A##1, 4) C4(A##2, 8) C4(A##3, 12) \
                    C4(A##4, 16) C4(A##5, 20) C4(A##6, 24) C4(A##7, 28) }

#define LOADX(p, A) { \
  const float4* xp_ = (const float4*)(src + (((p) >> 5) << 5)); \
  A##0 = xp_[0]; A##1 = xp_[1]; A##2 = xp_[2]; A##3 = xp_[3]; \
  A##4 = xp_[4]; A##5 = xp_[5]; A##6 = xp_[6]; A##7 = xp_[7]; }

__global__ __launch_bounds__(256, 2) void k_conv(
    const float* __restrict__ src, float* __restrict__ dst,
    const int* __restrict__ off, const int* __restrict__ pl,
    const int* __restrict__ perm, const float* __restrict__ W,
    const float* __restrict__ bias) {
  __shared__ unsigned int sWu[KVOL * WSTRIDE];   // 56160 B

  const int tid = threadIdx.x;
  // stage W -> bf16 pairs: slot i -> k = i/512, ci = (i%512)/16, qq = i%16 (co pair)
  for (int i = tid; i < KVOL * 512; i += 256) {
    int k = i >> 9;
    int r = i & 511;
    int ci = r >> 4;
    int qq = r & 15;
    float2 wv = *(const float2*)(W + k * 1024 + ci * 32 + qq * 2);
    sWu[k * WSTRIDE + r] = pk_bf16(wv.x, wv.y);
  }
  __syncthreads();

  const int g = tid >> 3;
  const int q2 = (tid & 7) * 2;
  const int pr = blockIdx.x * 32 + g;
  const bool active = pr < N_VOX;
  const int row = active ? perm[pr] : 0;
  const int beg = active ? off[row] : 0;
  const int end_ = active ? off[row + 1] : 0;

  float4 acc = {0.f, 0.f, 0.f, 0.f};
  float4 X0, X1, X2, X3, X4, X5, X6, X7;
  float4 Y0, Y1, Y2, Y3, Y4, Y5, Y6, Y7;

  if (beg < end_) {
    int e = beg;
    int p0 = pl[e];
    int pn = 0;
    LOADX(p0, X);
    while (true) {
      int en = e + 1;
      bool more = en < end_;
      if (more) { pn = pl[en]; LOADX(pn, Y); }
      { int kbase = (p0 & 31) * WSTRIDE; CALL32(X) }
      if (!more) break;
      e = en; p0 = pn;
      en = e + 1;
      more = en < end_;
      if (more) { pn = pl[en]; LOADX(pn, X); }
      { int kbase = (p0 & 31) * WSTRIDE; CALL32(Y) }
      if (!more) break;
      e = en; p0 = pn;
    }
  }

  if (active) {
    float4 bv = *(const float4*)(bias + (tid & 7) * 4);
    acc.x = fmaxf(acc.x + bv.x, 0.f);
    acc.y = fmaxf(acc.y + bv.y, 0.f);
    acc.z = fmaxf(acc.z + bv.z, 0.f);
    acc.w = fmaxf(acc.w + bv.w, 0.f);
    *(float4*)(dst + row * CH + (tid & 7) * 4) = acc;
  }
}

// ============================ logits kernel =================================
__global__ __launch_bounds__(256) void k_logits(
    const float* __restrict__ A, const float* __restrict__ B,
    const float* __restrict__ Wl, const float* __restrict__ bl,
    float* __restrict__ out) {
  __shared__ float sWl[CH * NCLS];
  __shared__ float sbl[NCLS];
  int tid = threadIdx.x;
  if (tid < CH * NCLS / 4) ((float4*)sWl)[tid] = ((const float4*)Wl)[tid];
  if (tid < NCLS) sbl[tid] = bl[tid];
  __syncthreads();

  int row = blockIdx.x * blockDim.x + tid;
  if (row >= N_VOX) return;

  float acc[NCLS];
#pragma unroll
  for (int j = 0; j < NCLS; j++) acc[j] = sbl[j];

  const float4* ra = (const float4*)(A + row * CH);
  const float4* rb = (const float4*)(B + row * CH);
#pragma unroll
  for (int c4 = 0; c4 < CH / 4; c4++) {
    float4 va = ra[c4];
    float4 vb = rb[c4];
    float x[4] = {va.x + vb.x, va.y + vb.y, va.z + vb.z, va.w + vb.w};
#pragma unroll
    for (int u = 0; u < 4; u++) {
      int c = c4 * 4 + u;
#pragma unroll
      for (int j = 0; j < NCLS; j++) acc[j] = fmaf(x[u], sWl[c * NCLS + j], acc[j]);
    }
  }
  float4* op = (float4*)(out + row * NCLS);
#pragma unroll
  for (int j5 = 0; j5 < NCLS / 4; j5++) {
    float4 v;
    v.x = acc[j5 * 4 + 0];
    v.y = acc[j5 * 4 + 1];
    v.z = acc[j5 * 4 + 2];
    v.w = acc[j5 * 4 + 3];
    op[j5] = v;
  }
}

// ============================ launch ========================================
extern "C" void kernel_launch(void* const* d_in, const int* in_sizes, int n_in,
                              void* d_out, int out_size, void* d_ws, size_t ws_size,
                              hipStream_t stream) {
  const float* in_feats = (const float*)d_in[0];
  const int*   ga       = (const int*)d_in[1];
  const int*   sa       = (const int*)d_in[2];
  const int*   gb       = (const int*)d_in[3];
  const int*   sb       = (const int*)d_in[4];
  const float* w1       = (const float*)d_in[5];
  const float* b1       = (const float*)d_in[6];
  const float* w1_2     = (const float*)d_in[7];
  const float* b1_2     = (const float*)d_in[8];
  const float* w2       = (const float*)d_in[9];
  const float* b2       = (const float*)d_in[10];
  const float* w3       = (const float*)d_in[11];
  const float* b3       = (const float*)d_in[12];
  const float* wl       = (const float*)d_in[13];
  const float* bl       = (const float*)d_in[14];
  float* out = (float*)d_out;

  // ---- workspace carve-up (~94.2 MB) ----
  char* w = (char*)d_ws;
  float* bufA = (float*)w;
  float* bufB = bufA + (size_t)N_VOX * CH;
  float* bufC = bufB + (size_t)N_VOX * CH;
  int* off_a  = (int*)(w + 57600000);
  int* off_b  = off_a + MPAD;
  int* cnt_a  = off_b + MPAD;      // hist, then reused as fill cursor
  int* cnt_b  = cnt_a + MPAD;
  int* perm_a = cnt_b + MPAD;
  int* perm_b = perm_a + MPAD;
  int* tmp    = perm_b + MPAD;
  int* part   = tmp + MPAD;        // 1024
  int* bins   = part + 1024;       // 256
  int* base_  = bins + 256;        // 256
  int* bcur   = base_ + 256;       // 256
  int* pl_a   = bcur + 256;        // TOT
  int* pl_b   = pl_a + TOT;

  dim3 blk(256);
  const int g_tot  = (TOT + 255) / 256;
  const int g_pad  = NPART;                 // MPAD/256
  const int g_conv = MPAD / 32;             // 4688
  const size_t cnt_bytes = (size_t)MPAD * sizeof(int);

  // ---- build inverted CSR + leveling perm for rulebook A ----
  hipMemsetAsync(cnt_a, 0, cnt_bytes, stream);
  k_hist<<<g_tot, blk, 0, stream>>>(sa, cnt_a);
  k_scan1<<<g_pad, blk, 0, stream>>>(cnt_a, tmp, part);
  k_scan2<<<1, 1024, 0, stream>>>(part);
  k_scan3<<<g_pad, blk, 0, stream>>>(tmp, part, off_a);
  hipMemsetAsync(cnt_a, 0, cnt_bytes, stream);
  k_fill<<<g_tot, blk, 0, stream>>>(ga, sa, off_a, cnt_a, pl_a);
  hipMemsetAsync(bins, 0, 256 * sizeof(int), stream);
  hipMemsetAsync(bcur, 0, 256 * sizeof(int), stream);
  k_lvlhist<<<g_pad, blk, 0, stream>>>(off_a, bins);
  k_lvlscan<<<1, 256, 0, stream>>>(bins, base_);
  k_lvlplace<<<g_pad, blk, 0, stream>>>(off_a, base_, bcur, perm_a);

  // ---- rulebook B ----
  hipMemsetAsync(cnt_b, 0, cnt_bytes, stream);
  k_hist<<<g_tot, blk, 0, stream>>>(sb, cnt_b);
  k_scan1<<<g_pad, blk, 0, stream>>>(cnt_b, tmp, part);
  k_scan2<<<1, 1024, 0, stream>>>(part);
  k_scan3<<<g_pad, blk, 0, stream>>>(tmp, part, off_b);
  hipMemsetAsync(cnt_b, 0, cnt_bytes, stream);
  k_fill<<<g_tot, blk, 0, stream>>>(gb, sb, off_b, cnt_b, pl_b);
  hipMemsetAsync(bins, 0, 256 * sizeof(int), stream);
  hipMemsetAsync(bcur, 0, 256 * sizeof(int), stream);
  k_lvlhist<<<g_pad, blk, 0, stream>>>(off_b, bins);
  k_lvlscan<<<1, 256, 0, stream>>>(bins, base_);
  k_lvlplace<<<g_pad, blk, 0, stream>>>(off_b, base_, bcur, perm_b);

  // ---- 4 fused conv layers (gather-only, no atomics) ----
  k_conv<<<g_conv, blk, 0, stream>>>(in_feats, bufA, off_a, pl_a, perm_a, w1, b1);
  k_conv<<<g_conv, blk, 0, stream>>>(bufA, bufB, off_b, pl_b, perm_b, w1_2, b1_2);
  k_conv<<<g_conv, blk, 0, stream>>>(in_feats, bufC, off_b, pl_b, perm_b, w2, b2);
  k_conv<<<g_conv, blk, 0, stream>>>(bufC, bufA, off_a, pl_a, perm_a, w3, b3);

  // ---- logits ----
  k_logits<<<(N_VOX + 255) / 256, blk, 0, stream>>>(bufB, bufA, wl, bl, out);
}